// Round 11
// baseline (1667.391 us; speedup 1.0000x reference)
//
#include <hip/hip_runtime.h>
#include <hip/hip_fp16.h>

// WaveNet forward, MI355X — round 16: r15 (best, 1665us) + v_cvt_pk_bf16_f32
// packing. The manual RNE f2bf bit-twiddle (~5 VALU ops/value) runs ~600
// ops/thread in k_block4's gate+res epilogues and ~120/thread in k_final.
// gfx950's v_cvt_pk_bf16_f32 (RNE, bit-identical) packs 2 floats in ONE
// instruction (no builtin — inline asm per the HW-verified T12 recipe).
// Everything else byte-identical to r15 (r5 GEMM structure + channel-pair
// fp16 skip [B][120][T][2] + FIRST-layer write + T14 batching + rcp
// activations + coalesced k_init2).
// B=4, T=32768, NM=80, RC=120, SC=240, NB=16, ND=8, NC=256. fp32 I/O.
// Path A (ws_size >= 160 MB): skip fp16 in d_ws. Path B: fp32 in d_out.

#define BSZ  4
#define TLEN 32768
#define NMEL 80
#define RCH  120
#define SCH  240
#define NBLK 16
#define NCLS 256
#define CP   128   // res channel pad
#define CC   96    // cond channel pad
#define TSB  128   // t-cols per k_block wg
#define TSF  64    // t-cols per k_final wg
#define OUTS 136   // LDS col stride for out tile
#define XES  264   // LDS col stride in k_final

typedef __attribute__((ext_vector_type(8))) short short8;
typedef __attribute__((ext_vector_type(4))) float floatx4;
#define MFMA16 __builtin_amdgcn_mfma_f32_16x16x32_bf16

__device__ __forceinline__ float bf2f(unsigned short u) {
    return __uint_as_float(((unsigned)u) << 16);
}
__device__ __forceinline__ unsigned short f2bf(float f) {
    unsigned x = __float_as_uint(f);
    return (unsigned short)((x + 0x7fffu + ((x >> 16) & 1u)) >> 16);  // rne
}
// One-instruction packed f32x2 -> bf16x2 (RNE, same result as f2bf pair).
__device__ __forceinline__ unsigned cvt_pk_bf16(float lo, float hi) {
    unsigned r;
    asm("v_cvt_pk_bf16_f32 %0, %1, %2" : "=v"(r) : "v"(lo), "v"(hi));
    return r;
}
__device__ __forceinline__ float h2f(unsigned short u) {
    return __half2float(__ushort_as_half(u));
}
__device__ __forceinline__ unsigned short f2h(float f) {
    return __half_as_ushort(__float2half(f));
}
// VALU-diet activations: hardware v_rcp_f32 instead of IEEE divide.
__device__ __forceinline__ float tanh_ap(float x) {
    x = fminf(fmaxf(x, -18.f), 18.f);
    float e = __expf(2.f * x);
    return (e - 1.f) * __builtin_amdgcn_rcpf(e + 1.f);
}
__device__ __forceinline__ float sigm_ap(float x) {
    x = fminf(fmaxf(x, -30.f), 30.f);
    return __builtin_amdgcn_rcpf(1.f + __expf(-x));
}

// ---- packed-weight geometry (unchanged) ------------------------------------
#define FR_BLK   257
#define FR_TOT   4368
#define NWELEM   (FR_TOT * 512)
#define BIA_BLK  608
#define NBELEM   (NBLK * BIA_BLK + 512)

__global__ void k_packw(const float* __restrict__ dil_w, const float* __restrict__ cond_w,
                        const float* __restrict__ skip_w, const float* __restrict__ res_w,
                        const float* __restrict__ out_w,  const float* __restrict__ end_w,
                        unsigned short* __restrict__ dst) {
    int idx = blockIdx.x * 256 + threadIdx.x;
    if (idx >= NWELEM) return;
    int fid = idx >> 9;
    int r   = idx & 511;
    int lane = r >> 3, j = r & 7;
    int m16 = lane & 15, q = lane >> 4;
    float v = 0.f;
    if (fid < NBLK * FR_BLK) {
        int blk = fid / FR_BLK, f = fid % FR_BLK;
        if (f < 165) {                      // gate: [240 interleaved][352]
            int mt = f / 11, ks = f % 11;
            int row = 16 * mt + m16;
            int kk  = ks * 32 + q * 8 + j;
            int c = row >> 1, br = row & 1;
            int srow = c + 120 * br;
            if (kk < 128) {
                if (kk < 120) v = dil_w[((size_t)(blk * 240 + srow) * 120 + kk) * 2 + 0];
            } else if (kk < 256) {
                int ch = kk - 128;
                if (ch < 120) v = dil_w[((size_t)(blk * 240 + srow) * 120 + ch) * 2 + 1];
            } else {
                int ch = kk - 256;
                if (ch < 80) v = cond_w[(size_t)(blk * 240 + srow) * 80 + ch];
            }
        } else if (f < 225) {               // skip: [240][128]
            int f2 = f - 165, mt = f2 / 4, ks = f2 % 4;
            int row = 16 * mt + m16;
            int kk = ks * 32 + q * 8 + j;
            if (kk < 120) v = skip_w[(size_t)(blk * 240 + row) * 120 + kk];
        } else {                            // res: [128][128]
            int f2 = f - 225, mt = f2 / 4, ks = f2 % 4;
            int row = 16 * mt + m16;
            int kk = ks * 32 + q * 8 + j;
            if (row < 120 && kk < 120) v = res_w[(size_t)(blk * 120 + row) * 120 + kk];
        }
    } else if (fid < NBLK * FR_BLK + 128) { // out_w
        int f = fid - NBLK * FR_BLK, mt = f / 8, ks = f % 8;
        int row = 16 * mt + m16;
        int kk = ks * 32 + q * 8 + j;
        if (kk < 240) v = out_w[(size_t)row * 240 + kk];
    } else {                                // end_w
        int f = fid - NBLK * FR_BLK - 128, mt = f / 8, ks = f % 8;
        int row = 16 * mt + m16;
        int kk = ks * 32 + q * 8 + j;
        v = end_w[(size_t)row * 256 + kk];
    }
    dst[idx] = f2bf(v);
}

__global__ void k_packb(const float* __restrict__ dil_b, const float* __restrict__ cond_b,
                        const float* __restrict__ skip_b, const float* __restrict__ res_b,
                        const float* __restrict__ out_b,  const float* __restrict__ end_b,
                        float* __restrict__ dst) {
    int idx = blockIdx.x * 256 + threadIdx.x;
    if (idx >= NBELEM) return;
    float v;
    if (idx < NBLK * BIA_BLK) {
        int blk = idx / BIA_BLK, f = idx % BIA_BLK;
        if (f < 240) {
            int c = f >> 1, br = f & 1;
            int srow = c + 120 * br;
            v = dil_b[blk * 240 + srow] + cond_b[blk * 240 + srow];
        } else if (f < 480) {
            v = skip_b[blk * 240 + (f - 240)];
        } else {
            int rr = f - 480;
            v = rr < 120 ? res_b[blk * 120 + rr] : 0.f;
        }
    } else {
        int f = idx - NBLK * BIA_BLK;
        v = f < 256 ? out_b[f] : end_b[f - 256];
    }
    dst[idx] = v;
}

// Coalesced init: lane j packs channel pair (2j, 2j+1) of row t.
__global__ void k_init2(const float* __restrict__ wav, const float* __restrict__ wav_w,
                        const float* __restrict__ wav_b, unsigned short* __restrict__ res) {
    int wid = blockIdx.x * 256 + threadIdx.x;   // B*T*64 work items
    int t = wid >> 6;
    int j = wid & 63;                            // dword (channel-pair) index
    float wv = wav[t];
    int c = 2 * j;
    unsigned out = 0u;
    if (c < RCH) {
        float v0 = wav_w[c] * wv + wav_b[c];
        float v1 = wav_w[c + 1] * wv + wav_b[c + 1];
        out = cvt_pk_bf16(v0, v1);
    }
    ((unsigned*)res)[(size_t)t * (CP / 2) + j] = out;
}

__global__ __launch_bounds__(256) void k_packc(const float* __restrict__ cond,
                                               unsigned short* __restrict__ dst) {
    __shared__ unsigned short CT[64 * CC];
    const int tid = threadIdx.x;
    const int t0 = blockIdx.x * 64;
    const int b = blockIdx.y;
    for (int i = tid; i < NMEL * 64; i += 256) {
        int c = i >> 6, tt = i & 63;
        CT[tt * CC + c] = f2bf(cond[((size_t)b * NMEL + c) * TLEN + t0 + tt]);
    }
    for (int i = tid; i < (CC - NMEL) * 64; i += 256) {
        int c = NMEL + (i >> 6), tt = i & 63;
        CT[tt * CC + c] = 0;
    }
    __syncthreads();
    unsigned* dp = (unsigned*)(dst + ((size_t)b * TLEN + t0) * CC);
    const unsigned* sp = (const unsigned*)CT;
    for (int i = tid; i < 64 * (CC / 2); i += 256) dp[i] = sp[i];
}

// ---- residual block (MFMA). r15 structure, cvt_pk_bf16 packing.
//      HF=true: fp16 skip in ws, channel-pair layout [B][120][T][2].
//      HF=false: fp32 skip in d_out [B][256][T] rows 0..239.
//      FIRST=true (layer 0): skip written, not RMW (no memset needed). ------
template <bool HF, bool FIRST>
__global__ __launch_bounds__(256, 2) void k_block4(
    const unsigned short* __restrict__ resIn,
    unsigned short* __restrict__ resOut,
    const unsigned short* __restrict__ condp,
    void* __restrict__ skipPtr,
    const unsigned short* __restrict__ wp,
    const float* __restrict__ bp,
    int d) {
    __shared__ __align__(16) unsigned short OUT[TSB * OUTS];
    __shared__ __align__(16) float BIAS[BIA_BLK];

    const int tid = threadIdx.x;
    const int lane = tid & 63;
    const int n = lane & 15, q = lane >> 4;
    const int w = __builtin_amdgcn_readfirstlane(tid >> 6);
    const int t0 = blockIdx.x * TSB;
    const int b = blockIdx.y;
    const size_t bT = (size_t)b * TLEN;

    for (int i = tid; i < BIA_BLK; i += 256) BIAS[i] = bp[i];
    for (int i = tid; i < TSB * 8; i += 256) {
        int col = i >> 3, ch = RCH + (i & 7);
        OUT[col * OUTS + ch] = 0;
    }

    const int mtb = w * 4;
    const int mtn = (w == 3) ? 3 : 4;
    const unsigned short* resb = resIn + bT * CP;
    const unsigned short* conb = condp + bT * CC;

    // ---------- gate GEMM: M=240(interleaved), K=352 ----------
    floatx4 acc[4][8];
#pragma unroll
    for (int mi = 0; mi < 4; mi++)
#pragma unroll
        for (int nt = 0; nt < 8; nt++) acc[mi][nt] = (floatx4){0.f, 0.f, 0.f, 0.f};

    for (int ks = 0; ks < 11; ks++) {
        short8 Bf[8];
        if (ks < 8) {
            const int dd = (ks < 4) ? d : 0;
            const int kl = (ks & 3) * 32 + q * 8;
            if (t0 >= TSB || dd == 0) {
#pragma unroll
                for (int nt = 0; nt < 8; nt++) {
                    int t = t0 + nt * 16 + n - dd;
                    Bf[nt] = *(const short8*)(resb + (size_t)t * CP + kl);
                }
            } else {
#pragma unroll
                for (int nt = 0; nt < 8; nt++) {
                    int t = t0 + nt * 16 + n - dd;
                    int tc = t < 0 ? 0 : t;
                    short8 v = *(const short8*)(resb + (size_t)tc * CP + kl);
                    if (t < 0) v = (short8){0, 0, 0, 0, 0, 0, 0, 0};
                    Bf[nt] = v;
                }
            }
        } else {
            const int kl = (ks - 8) * 32 + q * 8;
#pragma unroll
            for (int nt = 0; nt < 8; nt++) {
                int t = t0 + nt * 16 + n;
                Bf[nt] = *(const short8*)(conb + (size_t)t * CC + kl);
            }
        }
#pragma unroll
        for (int mi = 0; mi < 4; mi++) {
            if (mi < mtn) {
                short8 A = *(const short8*)(wp + ((size_t)((mtb + mi) * 11 + ks) * 64 + lane) * 8);
#pragma unroll
                for (int nt = 0; nt < 8; nt++)
                    acc[mi][nt] = MFMA16(A, Bf[nt], acc[mi][nt], 0, 0, 0);
            }
        }
    }

    // gating epilogue -> OUT
#pragma unroll
    for (int mi = 0; mi < 4; mi++) {
        if (mi < mtn) {
            int mt = mtb + mi;
            int p0 = 16 * mt + 4 * q;
            int ch = 8 * mt + 2 * q;
            float bt0 = BIAS[p0], bs0 = BIAS[p0 + 1];
            float bt1 = BIAS[p0 + 2], bs1 = BIAS[p0 + 3];
#pragma unroll
            for (int nt = 0; nt < 8; nt++) {
                int col = nt * 16 + n;
                float o0 = tanh_ap(acc[mi][nt][0] + bt0) * sigm_ap(acc[mi][nt][1] + bs0);
                float o1 = tanh_ap(acc[mi][nt][2] + bt1) * sigm_ap(acc[mi][nt][3] + bs1);
                *(unsigned*)&OUT[col * OUTS + ch] = cvt_pk_bf16(o0, o1);
            }
        }
    }
    __syncthreads();

    // ---------- skip GEMM: M=240, K=128 ----------
    {
        floatx4 acS[4][8];
#pragma unroll
        for (int mi = 0; mi < 4; mi++)
#pragma unroll
            for (int nt = 0; nt < 8; nt++) acS[mi][nt] = (floatx4){0.f, 0.f, 0.f, 0.f};
        for (int ks = 0; ks < 4; ks++) {
            short8 Bf[8];
#pragma unroll
            for (int nt = 0; nt < 8; nt++) {
                int col = nt * 16 + n;
                Bf[nt] = *(const short8*)&OUT[col * OUTS + ks * 32 + q * 8];
            }
#pragma unroll
            for (int mi = 0; mi < 4; mi++) {
                if (mi < mtn) {
                    short8 A = *(const short8*)(wp + ((size_t)(165 + (mtb + mi) * 4 + ks) * 64 + lane) * 8);
#pragma unroll
                    for (int nt = 0; nt < 8; nt++)
                        acS[mi][nt] = MFMA16(A, Bf[nt], acS[mi][nt], 0, 0, 0);
                }
            }
        }
#pragma unroll
        for (int mi = 0; mi < 4; mi++) {
            if (mi < mtn) {
                int mt = mtb + mi;
                int r0 = 16 * mt + 4 * q;           // multiple of 4
                floatx4 bb = *(const floatx4*)&BIAS[240 + r0];
                if (HF) {
                    // channel-pair layout: u32 row p = r0/2 holds ch {2p,2p+1}
                    unsigned* spb = (unsigned*)skipPtr +
                        ((size_t)(b * (SCH / 2)) + (r0 >> 1)) * TLEN + t0;
                    // T14 issue-early: batch all 16 loads before any use.
                    unsigned s0[8], s1[8];
                    if (!FIRST) {
#pragma unroll
                        for (int nt = 0; nt < 8; nt++) {
                            int tt = nt * 16 + n;
                            s0[nt] = spb[tt];
                            s1[nt] = spb[(size_t)TLEN + tt];
                        }
                    }
#pragma unroll
                    for (int nt = 0; nt < 8; nt++) {
                        int tt = nt * 16 + n;
                        float v0 = acS[mi][nt][0] + bb[0];
                        float v1 = acS[mi][nt][1] + bb[1];
                        float v2 = acS[mi][nt][2] + bb[2];
                        float v3 = acS[mi][nt][3] + bb[3];
                        if (!FIRST) {
                            v0 += h2f((unsigned short)(s0[nt] & 0xffff));
                            v1 += h2f((unsigned short)(s0[nt] >> 16));
                            v2 += h2f((unsigned short)(s1[nt] & 0xffff));
                            v3 += h2f((unsigned short)(s1[nt] >> 16));
                        }
                        spb[tt]                 = (unsigned)f2h(v0) | ((unsigned)f2h(v1) << 16);
                        spb[(size_t)TLEN + tt]  = (unsigned)f2h(v2) | ((unsigned)f2h(v3) << 16);
                    }
                } else {
#pragma unroll
                    for (int nt = 0; nt < 8; nt++) {
                        int t = t0 + nt * 16 + n;
                        float* sp = (float*)skipPtr + ((size_t)(b * NCLS) + r0) * TLEN + t;
#pragma unroll
                        for (int r = 0; r < 4; r++)
                            sp[(size_t)r * TLEN] += acS[mi][nt][r] + bb[r];
                    }
                }
            }
        }
    }

    // ---------- res GEMM: M=128(120), K=128, + residual ----------
    {
        floatx4 acR[2][8];
#pragma unroll
        for (int mi = 0; mi < 2; mi++)
#pragma unroll
            for (int nt = 0; nt < 8; nt++) acR[mi][nt] = (floatx4){0.f, 0.f, 0.f, 0.f};
        for (int ks = 0; ks < 4; ks++) {
            short8 Bf[8];
#pragma unroll
            for (int nt = 0; nt < 8; nt++) {
                int col = nt * 16 + n;
                Bf[nt] = *(const short8*)&OUT[col * OUTS + ks * 32 + q * 8];
            }
#pragma unroll
            for (int mi = 0; mi < 2; mi++) {
                short8 A = *(const short8*)(wp + ((size_t)(225 + (2 * w + mi) * 4 + ks) * 64 + lane) * 8);
#pragma unroll
                for (int nt = 0; nt < 8; nt++)
                    acR[mi][nt] = MFMA16(A, Bf[nt], acR[mi][nt], 0, 0, 0);
            }
        }
#pragma unroll
        for (int mi = 0; mi < 2; mi++) {
            int mt = 2 * w + mi;
            int r0 = 16 * mt + 4 * q;
            bool pad = (r0 >= RCH);
            floatx4 bb = *(const floatx4*)&BIAS[480 + r0];
            // T14 issue-early: batch the 8 residual-input loads.
            uint2 ri[8];
#pragma unroll
            for (int nt = 0; nt < 8; nt++) {
                int t = t0 + nt * 16 + n;
                ri[nt] = *(const uint2*)(resIn + (bT + t) * CP + r0);
            }
#pragma unroll
            for (int nt = 0; nt < 8; nt++) {
                int t = t0 + nt * 16 + n;
                unsigned short* rop = resOut + (bT + t) * CP + r0;
                float v0 = acR[mi][nt][0] + bb[0] + bf2f((unsigned short)(ri[nt].x & 0xffff));
                float v1 = acR[mi][nt][1] + bb[1] + bf2f((unsigned short)(ri[nt].x >> 16));
                float v2 = acR[mi][nt][2] + bb[2] + bf2f((unsigned short)(ri[nt].y & 0xffff));
                float v3 = acR[mi][nt][3] + bb[3] + bf2f((unsigned short)(ri[nt].y >> 16));
                uint2 ov;
                ov.x = pad ? 0u : cvt_pk_bf16(v0, v1);
                ov.y = pad ? 0u : cvt_pk_bf16(v2, v3);
                *(uint2*)rop = ov;
            }
        }
    }
}

// ---- final. HF=true: read fp16 skip pair-layout [B][120][T][2], write fp32
//      d_out. HF=false: in-place fp32 in d_out. -----------------------------
template <bool HF>
__global__ __launch_bounds__(256, 2) void k_final4(
    const void* __restrict__ skipPtr,
    float* __restrict__ io,
    const unsigned short* __restrict__ wpO,
    const unsigned short* __restrict__ wpE,
    const float* __restrict__ bpF) {
    __shared__ __align__(16) unsigned short X[TSF * XES];
    __shared__ __align__(16) unsigned short E[TSF * XES];
    __shared__ float BF[512];

    const int tid = threadIdx.x;
    const int lane = tid & 63;
    const int n = lane & 15, q = lane >> 4;
    const int w = __builtin_amdgcn_readfirstlane(tid >> 6);
    const int t0 = blockIdx.x * TSF;
    const int b = blockIdx.y;

    for (int i = tid; i < 512; i += 256) BF[i] = bpF[i];
    if (HF) {
        // pair layout: u32 row p holds channels {2p, 2p+1}; cols coalesced.
        const unsigned* su = (const unsigned*)skipPtr;
        for (int i = tid; i < (SCH / 2) * TSF; i += 256) {
            int p = i >> 6, col = i & 63;   // TSF == 64
            unsigned v = su[((size_t)(b * (SCH / 2)) + p) * TLEN + t0 + col];
            float f0 = fmaxf(h2f((unsigned short)(v & 0xffff)), 0.f);
            float f1 = fmaxf(h2f((unsigned short)(v >> 16)), 0.f);
            *(unsigned*)&X[col * XES + 2 * p] = cvt_pk_bf16(f0, f1);
        }
    } else {
        for (int i = tid; i < SCH * TSF; i += 256) {
            int row = i >> 6, col = i & 63;
            float v = io[((size_t)(b * NCLS) + row) * TLEN + t0 + col];
            X[col * XES + row] = f2bf(fmaxf(v, 0.f));
        }
    }
    for (int i = tid; i < (NCLS - SCH) * TSF; i += 256) {
        int row = SCH + (i >> 6), col = i & 63;
        X[col * XES + row] = 0;
    }
    __syncthreads();

    const int mtb = w * 4;
    {
        floatx4 acc[4][4];
#pragma unroll
        for (int mi = 0; mi < 4; mi++)
#pragma unroll
            for (int nt = 0; nt < 4; nt++) acc[mi][nt] = (floatx4){0.f, 0.f, 0.f, 0.f};
        for (int ks = 0; ks < 8; ks++) {
            short8 Bf[4];
#pragma unroll
            for (int nt = 0; nt < 4; nt++) {
                int col = nt * 16 + n;
                Bf[nt] = *(const short8*)&X[col * XES + ks * 32 + q * 8];
            }
#pragma unroll
            for (int mi = 0; mi < 4; mi++) {
                short8 A = *(const short8*)(wpO + ((size_t)((mtb + mi) * 8 + ks) * 64 + lane) * 8);
#pragma unroll
                for (int nt = 0; nt < 4; nt++)
                    acc[mi][nt] = MFMA16(A, Bf[nt], acc[mi][nt], 0, 0, 0);
            }
        }
#pragma unroll
        for (int mi = 0; mi < 4; mi++) {
            int ch0 = 16 * (mtb + mi) + 4 * q;
#pragma unroll
            for (int nt = 0; nt < 4; nt++) {
                int col = nt * 16 + n;
                float v0 = fmaxf(acc[mi][nt][0] + BF[ch0], 0.f);
                float v1 = fmaxf(acc[mi][nt][1] + BF[ch0 + 1], 0.f);
                float v2 = fmaxf(acc[mi][nt][2] + BF[ch0 + 2], 0.f);
                float v3 = fmaxf(acc[mi][nt][3] + BF[ch0 + 3], 0.f);
                *(unsigned*)&E[col * XES + ch0]     = cvt_pk_bf16(v0, v1);
                *(unsigned*)&E[col * XES + ch0 + 2] = cvt_pk_bf16(v2, v3);
            }
        }
    }
    __syncthreads();
    {
        floatx4 acc[4][4];
#pragma unroll
        for (int mi = 0; mi < 4; mi++)
#pragma unroll
            for (int nt = 0; nt < 4; nt++) acc[mi][nt] = (floatx4){0.f, 0.f, 0.f, 0.f};
        for (int ks = 0; ks < 8; ks++) {
            short8 Bf[4];
#pragma unroll
            for (int nt = 0; nt < 4; nt++) {
                int col = nt * 16 + n;
                Bf[nt] = *(const short8*)&E[col * XES + ks * 32 + q * 8];
            }
#pragma unroll
            for (int mi = 0; mi < 4; mi++) {
                short8 A = *(const short8*)(wpE + ((size_t)((mtb + mi) * 8 + ks) * 64 + lane) * 8);
#pragma unroll
                for (int nt = 0; nt < 4; nt++)
                    acc[mi][nt] = MFMA16(A, Bf[nt], acc[mi][nt], 0, 0, 0);
            }
        }
#pragma unroll
        for (int mi = 0; mi < 4; mi++) {
            int r0 = 16 * (mtb + mi) + 4 * q;
#pragma unroll
            for (int nt = 0; nt < 4; nt++) {
                int t = t0 + nt * 16 + n;
#pragma unroll
                for (int r = 0; r < 4; r++)
                    io[((size_t)(b * NCLS) + r0 + r) * TLEN + t] =
                        acc[mi][nt][r] + BF[256 + r0 + r];
            }
        }
    }
}

extern "C" void kernel_launch(void* const* d_in, const int* in_sizes, int n_in,
                              void* d_out, int out_size, void* d_ws, size_t ws_size,
                              hipStream_t stream) {
    (void)in_sizes; (void)n_in;
    const float* wav    = (const float*)d_in[0];
    const float* cond   = (const float*)d_in[1];
    const float* wav_w  = (const float*)d_in[2];
    const float* wav_b  = (const float*)d_in[3];
    const float* cond_w = (const float*)d_in[4];
    const float* cond_b = (const float*)d_in[5];
    const float* dil_w  = (const float*)d_in[6];
    const float* dil_b  = (const float*)d_in[7];
    const float* skip_w = (const float*)d_in[8];
    const float* skip_b = (const float*)d_in[9];
    const float* res_w  = (const float*)d_in[10];
    const float* res_b  = (const float*)d_in[11];
    const float* out_w  = (const float*)d_in[12];
    const float* out_b  = (const float*)d_in[13];
    const float* end_w  = (const float*)d_in[14];
    const float* end_b  = (const float*)d_in[15];

    const size_t resElems = (size_t)BSZ * TLEN * CP;       // 16,777,216
    unsigned short* resA  = (unsigned short*)d_ws;
    unsigned short* resB  = resA + resElems;
    unsigned short* condp = resB + resElems;
    unsigned short* wp    = condp + (size_t)BSZ * TLEN * CC;
    float* bp             = (float*)(wp + (size_t)FR_TOT * 512);
    unsigned short* skipH = (unsigned short*)(bp + NBELEM);
    const size_t skipHBytes = (size_t)BSZ * SCH * TLEN * 2;  // 62,914,560
    const size_t needA = (size_t)((char*)(skipH) - (char*)d_ws) + skipHBytes;  // ~160 MB
    const bool hf = ws_size >= needA;

    void* skipPtr = hf ? (void*)skipH : (void*)d_out;
    // HF path: layer 0 WRITES skip (FIRST=true) -> no memset needed.
    if (!hf) hipMemsetAsync(d_out, 0, (size_t)out_size * sizeof(float), stream);

    k_packw<<<dim3((NWELEM + 255) / 256), 256, 0, stream>>>(
        dil_w, cond_w, skip_w, res_w, out_w, end_w, wp);
    k_packb<<<dim3((NBELEM + 255) / 256), 256, 0, stream>>>(
        dil_b, cond_b, skip_b, res_b, out_b, end_b, bp);
    k_init2<<<dim3(BSZ * TLEN / 4), 256, 0, stream>>>(wav, wav_w, wav_b, resA);
    k_packc<<<dim3(TLEN / 64, BSZ), 256, 0, stream>>>(cond, condp);

    unsigned short* rin = resA;
    unsigned short* rout = resB;
    for (int i = 0; i < NBLK; i++) {
        int d = 1 << (i & 7);
        if (hf) {
            if (i == 0)
                k_block4<true, true><<<dim3(TLEN / TSB, BSZ), 256, 0, stream>>>(
                    rin, rout, condp, skipPtr,
                    wp + (size_t)i * FR_BLK * 512, bp + (size_t)i * BIA_BLK, d);
            else
                k_block4<true, false><<<dim3(TLEN / TSB, BSZ), 256, 0, stream>>>(
                    rin, rout, condp, skipPtr,
                    wp + (size_t)i * FR_BLK * 512, bp + (size_t)i * BIA_BLK, d);
        } else {
            k_block4<false, false><<<dim3(TLEN / TSB, BSZ), 256, 0, stream>>>(
                rin, rout, condp, skipPtr,
                wp + (size_t)i * FR_BLK * 512, bp + (size_t)i * BIA_BLK, d);
        }
        unsigned short* tmp = rin; rin = rout; rout = tmp;
    }
    if (hf)
        k_final4<true><<<dim3(TLEN / TSF, BSZ), 256, 0, stream>>>(
            skipPtr, (float*)d_out,
            wp + (size_t)(NBLK * FR_BLK) * 512,
            wp + (size_t)(NBLK * FR_BLK + 128) * 512,
            bp + NBLK * BIA_BLK);
    else
        k_final4<false><<<dim3(TLEN / TSF, BSZ), 256, 0, stream>>>(
            skipPtr, (float*)d_out,
            wp + (size_t)(NBLK * FR_BLK) * 512,
            wp + (size_t)(NBLK * FR_BLK + 128) * 512,
            bp + NBLK * BIA_BLK);
}

// Round 12
// 1645.042 us; speedup vs baseline: 1.0136x; 1.0136x over previous
//
#include <hip/hip_runtime.h>
#include <hip/hip_fp16.h>

// WaveNet forward, MI355X — round 17: r16 + channel-QUAD skip layout.
// Skip fp16 buffer is [B][60][T][4]: uint2 row p holds channels {4p..4p+3}
// at time t. The MFMA quad (r0..r0+3, r0 % 4 == 0) is ONE uint2 load + ONE
// uint2 store (was 2+2 u32 in the pair layout) — per-thread skip VMEM ops
// halve, each wave op covers 128B contiguous (2 full lines).
// Rest identical to r16 (r5 GEMM structure + FIRST-layer write + T14
// batching + rcp activations + cvt_pk_bf16 packing + coalesced k_init2).
// B=4, T=32768, NM=80, RC=120, SC=240, NB=16, ND=8, NC=256. fp32 I/O.
// Path A (ws_size >= 160 MB): skip fp16 in d_ws. Path B: fp32 in d_out.

#define BSZ  4
#define TLEN 32768
#define NMEL 80
#define RCH  120
#define SCH  240
#define NBLK 16
#define NCLS 256
#define CP   128   // res channel pad
#define CC   96    // cond channel pad
#define TSB  128   // t-cols per k_block wg
#define TSF  64    // t-cols per k_final wg
#define OUTS 136   // LDS col stride for out tile
#define XES  264   // LDS col stride in k_final

typedef __attribute__((ext_vector_type(8))) short short8;
typedef __attribute__((ext_vector_type(4))) float floatx4;
#define MFMA16 __builtin_amdgcn_mfma_f32_16x16x32_bf16

__device__ __forceinline__ float bf2f(unsigned short u) {
    return __uint_as_float(((unsigned)u) << 16);
}
__device__ __forceinline__ unsigned short f2bf(float f) {
    unsigned x = __float_as_uint(f);
    return (unsigned short)((x + 0x7fffu + ((x >> 16) & 1u)) >> 16);  // rne
}
// One-instruction packed f32x2 -> bf16x2 (RNE, same result as f2bf pair).
__device__ __forceinline__ unsigned cvt_pk_bf16(float lo, float hi) {
    unsigned r;
    asm("v_cvt_pk_bf16_f32 %0, %1, %2" : "=v"(r) : "v"(lo), "v"(hi));
    return r;
}
__device__ __forceinline__ float h2f(unsigned short u) {
    return __half2float(__ushort_as_half(u));
}
__device__ __forceinline__ unsigned short f2h(float f) {
    return __half_as_ushort(__float2half(f));
}
// VALU-diet activations: hardware v_rcp_f32 instead of IEEE divide.
__device__ __forceinline__ float tanh_ap(float x) {
    x = fminf(fmaxf(x, -18.f), 18.f);
    float e = __expf(2.f * x);
    return (e - 1.f) * __builtin_amdgcn_rcpf(e + 1.f);
}
__device__ __forceinline__ float sigm_ap(float x) {
    x = fminf(fmaxf(x, -30.f), 30.f);
    return __builtin_amdgcn_rcpf(1.f + __expf(-x));
}

// ---- packed-weight geometry (unchanged) ------------------------------------
#define FR_BLK   257
#define FR_TOT   4368
#define NWELEM   (FR_TOT * 512)
#define BIA_BLK  608
#define NBELEM   (NBLK * BIA_BLK + 512)

__global__ void k_packw(const float* __restrict__ dil_w, const float* __restrict__ cond_w,
                        const float* __restrict__ skip_w, const float* __restrict__ res_w,
                        const float* __restrict__ out_w,  const float* __restrict__ end_w,
                        unsigned short* __restrict__ dst) {
    int idx = blockIdx.x * 256 + threadIdx.x;
    if (idx >= NWELEM) return;
    int fid = idx >> 9;
    int r   = idx & 511;
    int lane = r >> 3, j = r & 7;
    int m16 = lane & 15, q = lane >> 4;
    float v = 0.f;
    if (fid < NBLK * FR_BLK) {
        int blk = fid / FR_BLK, f = fid % FR_BLK;
        if (f < 165) {                      // gate: [240 interleaved][352]
            int mt = f / 11, ks = f % 11;
            int row = 16 * mt + m16;
            int kk  = ks * 32 + q * 8 + j;
            int c = row >> 1, br = row & 1;
            int srow = c + 120 * br;
            if (kk < 128) {
                if (kk < 120) v = dil_w[((size_t)(blk * 240 + srow) * 120 + kk) * 2 + 0];
            } else if (kk < 256) {
                int ch = kk - 128;
                if (ch < 120) v = dil_w[((size_t)(blk * 240 + srow) * 120 + ch) * 2 + 1];
            } else {
                int ch = kk - 256;
                if (ch < 80) v = cond_w[(size_t)(blk * 240 + srow) * 80 + ch];
            }
        } else if (f < 225) {               // skip: [240][128]
            int f2 = f - 165, mt = f2 / 4, ks = f2 % 4;
            int row = 16 * mt + m16;
            int kk = ks * 32 + q * 8 + j;
            if (kk < 120) v = skip_w[(size_t)(blk * 240 + row) * 120 + kk];
        } else {                            // res: [128][128]
            int f2 = f - 225, mt = f2 / 4, ks = f2 % 4;
            int row = 16 * mt + m16;
            int kk = ks * 32 + q * 8 + j;
            if (row < 120 && kk < 120) v = res_w[(size_t)(blk * 120 + row) * 120 + kk];
        }
    } else if (fid < NBLK * FR_BLK + 128) { // out_w
        int f = fid - NBLK * FR_BLK, mt = f / 8, ks = f % 8;
        int row = 16 * mt + m16;
        int kk = ks * 32 + q * 8 + j;
        if (kk < 240) v = out_w[(size_t)row * 240 + kk];
    } else {                                // end_w
        int f = fid - NBLK * FR_BLK - 128, mt = f / 8, ks = f % 8;
        int row = 16 * mt + m16;
        int kk = ks * 32 + q * 8 + j;
        v = end_w[(size_t)row * 256 + kk];
    }
    dst[idx] = f2bf(v);
}

__global__ void k_packb(const float* __restrict__ dil_b, const float* __restrict__ cond_b,
                        const float* __restrict__ skip_b, const float* __restrict__ res_b,
                        const float* __restrict__ out_b,  const float* __restrict__ end_b,
                        float* __restrict__ dst) {
    int idx = blockIdx.x * 256 + threadIdx.x;
    if (idx >= NBELEM) return;
    float v;
    if (idx < NBLK * BIA_BLK) {
        int blk = idx / BIA_BLK, f = idx % BIA_BLK;
        if (f < 240) {
            int c = f >> 1, br = f & 1;
            int srow = c + 120 * br;
            v = dil_b[blk * 240 + srow] + cond_b[blk * 240 + srow];
        } else if (f < 480) {
            v = skip_b[blk * 240 + (f - 240)];
        } else {
            int rr = f - 480;
            v = rr < 120 ? res_b[blk * 120 + rr] : 0.f;
        }
    } else {
        int f = idx - NBLK * BIA_BLK;
        v = f < 256 ? out_b[f] : end_b[f - 256];
    }
    dst[idx] = v;
}

// Coalesced init: lane j packs channel pair (2j, 2j+1) of row t.
__global__ void k_init2(const float* __restrict__ wav, const float* __restrict__ wav_w,
                        const float* __restrict__ wav_b, unsigned short* __restrict__ res) {
    int wid = blockIdx.x * 256 + threadIdx.x;   // B*T*64 work items
    int t = wid >> 6;
    int j = wid & 63;                            // dword (channel-pair) index
    float wv = wav[t];
    int c = 2 * j;
    unsigned out = 0u;
    if (c < RCH) {
        float v0 = wav_w[c] * wv + wav_b[c];
        float v1 = wav_w[c + 1] * wv + wav_b[c + 1];
        out = cvt_pk_bf16(v0, v1);
    }
    ((unsigned*)res)[(size_t)t * (CP / 2) + j] = out;
}

__global__ __launch_bounds__(256) void k_packc(const float* __restrict__ cond,
                                               unsigned short* __restrict__ dst) {
    __shared__ unsigned short CT[64 * CC];
    const int tid = threadIdx.x;
    const int t0 = blockIdx.x * 64;
    const int b = blockIdx.y;
    for (int i = tid; i < NMEL * 64; i += 256) {
        int c = i >> 6, tt = i & 63;
        CT[tt * CC + c] = f2bf(cond[((size_t)b * NMEL + c) * TLEN + t0 + tt]);
    }
    for (int i = tid; i < (CC - NMEL) * 64; i += 256) {
        int c = NMEL + (i >> 6), tt = i & 63;
        CT[tt * CC + c] = 0;
    }
    __syncthreads();
    unsigned* dp = (unsigned*)(dst + ((size_t)b * TLEN + t0) * CC);
    const unsigned* sp = (const unsigned*)CT;
    for (int i = tid; i < 64 * (CC / 2); i += 256) dp[i] = sp[i];
}

// ---- residual block (MFMA). r16 structure, channel-quad skip layout.
//      HF=true: fp16 skip in ws, [B][60][T][4]: uint2 row p = ch {4p..4p+3}.
//      HF=false: fp32 skip in d_out [B][256][T] rows 0..239.
//      FIRST=true (layer 0): skip written, not RMW (no memset needed). ------
template <bool HF, bool FIRST>
__global__ __launch_bounds__(256, 2) void k_block4(
    const unsigned short* __restrict__ resIn,
    unsigned short* __restrict__ resOut,
    const unsigned short* __restrict__ condp,
    void* __restrict__ skipPtr,
    const unsigned short* __restrict__ wp,
    const float* __restrict__ bp,
    int d) {
    __shared__ __align__(16) unsigned short OUT[TSB * OUTS];
    __shared__ __align__(16) float BIAS[BIA_BLK];

    const int tid = threadIdx.x;
    const int lane = tid & 63;
    const int n = lane & 15, q = lane >> 4;
    const int w = __builtin_amdgcn_readfirstlane(tid >> 6);
    const int t0 = blockIdx.x * TSB;
    const int b = blockIdx.y;
    const size_t bT = (size_t)b * TLEN;

    for (int i = tid; i < BIA_BLK; i += 256) BIAS[i] = bp[i];
    for (int i = tid; i < TSB * 8; i += 256) {
        int col = i >> 3, ch = RCH + (i & 7);
        OUT[col * OUTS + ch] = 0;
    }

    const int mtb = w * 4;
    const int mtn = (w == 3) ? 3 : 4;
    const unsigned short* resb = resIn + bT * CP;
    const unsigned short* conb = condp + bT * CC;

    // ---------- gate GEMM: M=240(interleaved), K=352 ----------
    floatx4 acc[4][8];
#pragma unroll
    for (int mi = 0; mi < 4; mi++)
#pragma unroll
        for (int nt = 0; nt < 8; nt++) acc[mi][nt] = (floatx4){0.f, 0.f, 0.f, 0.f};

    for (int ks = 0; ks < 11; ks++) {
        short8 Bf[8];
        if (ks < 8) {
            const int dd = (ks < 4) ? d : 0;
            const int kl = (ks & 3) * 32 + q * 8;
            if (t0 >= TSB || dd == 0) {
#pragma unroll
                for (int nt = 0; nt < 8; nt++) {
                    int t = t0 + nt * 16 + n - dd;
                    Bf[nt] = *(const short8*)(resb + (size_t)t * CP + kl);
                }
            } else {
#pragma unroll
                for (int nt = 0; nt < 8; nt++) {
                    int t = t0 + nt * 16 + n - dd;
                    int tc = t < 0 ? 0 : t;
                    short8 v = *(const short8*)(resb + (size_t)tc * CP + kl);
                    if (t < 0) v = (short8){0, 0, 0, 0, 0, 0, 0, 0};
                    Bf[nt] = v;
                }
            }
        } else {
            const int kl = (ks - 8) * 32 + q * 8;
#pragma unroll
            for (int nt = 0; nt < 8; nt++) {
                int t = t0 + nt * 16 + n;
                Bf[nt] = *(const short8*)(conb + (size_t)t * CC + kl);
            }
        }
#pragma unroll
        for (int mi = 0; mi < 4; mi++) {
            if (mi < mtn) {
                short8 A = *(const short8*)(wp + ((size_t)((mtb + mi) * 11 + ks) * 64 + lane) * 8);
#pragma unroll
                for (int nt = 0; nt < 8; nt++)
                    acc[mi][nt] = MFMA16(A, Bf[nt], acc[mi][nt], 0, 0, 0);
            }
        }
    }

    // gating epilogue -> OUT
#pragma unroll
    for (int mi = 0; mi < 4; mi++) {
        if (mi < mtn) {
            int mt = mtb + mi;
            int p0 = 16 * mt + 4 * q;
            int ch = 8 * mt + 2 * q;
            float bt0 = BIAS[p0], bs0 = BIAS[p0 + 1];
            float bt1 = BIAS[p0 + 2], bs1 = BIAS[p0 + 3];
#pragma unroll
            for (int nt = 0; nt < 8; nt++) {
                int col = nt * 16 + n;
                float o0 = tanh_ap(acc[mi][nt][0] + bt0) * sigm_ap(acc[mi][nt][1] + bs0);
                float o1 = tanh_ap(acc[mi][nt][2] + bt1) * sigm_ap(acc[mi][nt][3] + bs1);
                *(unsigned*)&OUT[col * OUTS + ch] = cvt_pk_bf16(o0, o1);
            }
        }
    }
    __syncthreads();

    // ---------- skip GEMM: M=240, K=128 ----------
    {
        floatx4 acS[4][8];
#pragma unroll
        for (int mi = 0; mi < 4; mi++)
#pragma unroll
            for (int nt = 0; nt < 8; nt++) acS[mi][nt] = (floatx4){0.f, 0.f, 0.f, 0.f};
        for (int ks = 0; ks < 4; ks++) {
            short8 Bf[8];
#pragma unroll
            for (int nt = 0; nt < 8; nt++) {
                int col = nt * 16 + n;
                Bf[nt] = *(const short8*)&OUT[col * OUTS + ks * 32 + q * 8];
            }
#pragma unroll
            for (int mi = 0; mi < 4; mi++) {
                if (mi < mtn) {
                    short8 A = *(const short8*)(wp + ((size_t)(165 + (mtb + mi) * 4 + ks) * 64 + lane) * 8);
#pragma unroll
                    for (int nt = 0; nt < 8; nt++)
                        acS[mi][nt] = MFMA16(A, Bf[nt], acS[mi][nt], 0, 0, 0);
                }
            }
        }
#pragma unroll
        for (int mi = 0; mi < 4; mi++) {
            if (mi < mtn) {
                int mt = mtb + mi;
                int r0 = 16 * mt + 4 * q;           // multiple of 4
                floatx4 bb = *(const floatx4*)&BIAS[240 + r0];
                if (HF) {
                    // channel-quad layout: uint2 row p = r0/4 holds ch {4p..4p+3}
                    uint2* spb = (uint2*)skipPtr +
                        ((size_t)(b * (SCH / 4)) + (r0 >> 2)) * TLEN + t0;
                    // T14 issue-early: batch all 8 loads before any use.
                    uint2 s[8];
                    if (!FIRST) {
#pragma unroll
                        for (int nt = 0; nt < 8; nt++)
                            s[nt] = spb[nt * 16 + n];
                    }
#pragma unroll
                    for (int nt = 0; nt < 8; nt++) {
                        float v0 = acS[mi][nt][0] + bb[0];
                        float v1 = acS[mi][nt][1] + bb[1];
                        float v2 = acS[mi][nt][2] + bb[2];
                        float v3 = acS[mi][nt][3] + bb[3];
                        if (!FIRST) {
                            v0 += h2f((unsigned short)(s[nt].x & 0xffff));
                            v1 += h2f((unsigned short)(s[nt].x >> 16));
                            v2 += h2f((unsigned short)(s[nt].y & 0xffff));
                            v3 += h2f((unsigned short)(s[nt].y >> 16));
                        }
                        uint2 ov;
                        ov.x = (unsigned)f2h(v0) | ((unsigned)f2h(v1) << 16);
                        ov.y = (unsigned)f2h(v2) | ((unsigned)f2h(v3) << 16);
                        spb[nt * 16 + n] = ov;
                    }
                } else {
#pragma unroll
                    for (int nt = 0; nt < 8; nt++) {
                        int t = t0 + nt * 16 + n;
                        float* sp = (float*)skipPtr + ((size_t)(b * NCLS) + r0) * TLEN + t;
#pragma unroll
                        for (int r = 0; r < 4; r++)
                            sp[(size_t)r * TLEN] += acS[mi][nt][r] + bb[r];
                    }
                }
            }
        }
    }

    // ---------- res GEMM: M=128(120), K=128, + residual ----------
    {
        floatx4 acR[2][8];
#pragma unroll
        for (int mi = 0; mi < 2; mi++)
#pragma unroll
            for (int nt = 0; nt < 8; nt++) acR[mi][nt] = (floatx4){0.f, 0.f, 0.f, 0.f};
        for (int ks = 0; ks < 4; ks++) {
            short8 Bf[8];
#pragma unroll
            for (int nt = 0; nt < 8; nt++) {
                int col = nt * 16 + n;
                Bf[nt] = *(const short8*)&OUT[col * OUTS + ks * 32 + q * 8];
            }
#pragma unroll
            for (int mi = 0; mi < 2; mi++) {
                short8 A = *(const short8*)(wp + ((size_t)(225 + (2 * w + mi) * 4 + ks) * 64 + lane) * 8);
#pragma unroll
                for (int nt = 0; nt < 8; nt++)
                    acR[mi][nt] = MFMA16(A, Bf[nt], acR[mi][nt], 0, 0, 0);
            }
        }
#pragma unroll
        for (int mi = 0; mi < 2; mi++) {
            int mt = 2 * w + mi;
            int r0 = 16 * mt + 4 * q;
            bool pad = (r0 >= RCH);
            floatx4 bb = *(const floatx4*)&BIAS[480 + r0];
            // T14 issue-early: batch the 8 residual-input loads.
            uint2 ri[8];
#pragma unroll
            for (int nt = 0; nt < 8; nt++) {
                int t = t0 + nt * 16 + n;
                ri[nt] = *(const uint2*)(resIn + (bT + t) * CP + r0);
            }
#pragma unroll
            for (int nt = 0; nt < 8; nt++) {
                int t = t0 + nt * 16 + n;
                unsigned short* rop = resOut + (bT + t) * CP + r0;
                float v0 = acR[mi][nt][0] + bb[0] + bf2f((unsigned short)(ri[nt].x & 0xffff));
                float v1 = acR[mi][nt][1] + bb[1] + bf2f((unsigned short)(ri[nt].x >> 16));
                float v2 = acR[mi][nt][2] + bb[2] + bf2f((unsigned short)(ri[nt].y & 0xffff));
                float v3 = acR[mi][nt][3] + bb[3] + bf2f((unsigned short)(ri[nt].y >> 16));
                uint2 ov;
                ov.x = pad ? 0u : cvt_pk_bf16(v0, v1);
                ov.y = pad ? 0u : cvt_pk_bf16(v2, v3);
                *(uint2*)rop = ov;
            }
        }
    }
}

// ---- final. HF=true: read fp16 skip quad-layout [B][60][T][4], write fp32
//      d_out. HF=false: in-place fp32 in d_out. -----------------------------
template <bool HF>
__global__ __launch_bounds__(256, 2) void k_final4(
    const void* __restrict__ skipPtr,
    float* __restrict__ io,
    const unsigned short* __restrict__ wpO,
    const unsigned short* __restrict__ wpE,
    const float* __restrict__ bpF) {
    __shared__ __align__(16) unsigned short X[TSF * XES];
    __shared__ __align__(16) unsigned short E[TSF * XES];
    __shared__ float BF[512];

    const int tid = threadIdx.x;
    const int lane = tid & 63;
    const int n = lane & 15, q = lane >> 4;
    const int w = __builtin_amdgcn_readfirstlane(tid >> 6);
    const int t0 = blockIdx.x * TSF;
    const int b = blockIdx.y;

    for (int i = tid; i < 512; i += 256) BF[i] = bpF[i];
    if (HF) {
        // quad layout: uint2 row p holds channels {4p..4p+3}; cols coalesced.
        const uint2* su = (const uint2*)skipPtr;
        for (int i = tid; i < (SCH / 4) * TSF; i += 256) {   // 60*64
            int p = i >> 6, col = i & 63;   // TSF == 64
            uint2 v = su[((size_t)(b * (SCH / 4)) + p) * TLEN + t0 + col];
            float f0 = fmaxf(h2f((unsigned short)(v.x & 0xffff)), 0.f);
            float f1 = fmaxf(h2f((unsigned short)(v.x >> 16)), 0.f);
            float f2 = fmaxf(h2f((unsigned short)(v.y & 0xffff)), 0.f);
            float f3 = fmaxf(h2f((unsigned short)(v.y >> 16)), 0.f);
            uint2 ov;
            ov.x = cvt_pk_bf16(f0, f1);
            ov.y = cvt_pk_bf16(f2, f3);
            *(uint2*)&X[col * XES + 4 * p] = ov;
        }
    } else {
        for (int i = tid; i < SCH * TSF; i += 256) {
            int row = i >> 6, col = i & 63;
            float v = io[((size_t)(b * NCLS) + row) * TLEN + t0 + col];
            X[col * XES + row] = f2bf(fmaxf(v, 0.f));
        }
    }
    for (int i = tid; i < (NCLS - SCH) * TSF; i += 256) {
        int row = SCH + (i >> 6), col = i & 63;
        X[col * XES + row] = 0;
    }
    __syncthreads();

    const int mtb = w * 4;
    {
        floatx4 acc[4][4];
#pragma unroll
        for (int mi = 0; mi < 4; mi++)
#pragma unroll
            for (int nt = 0; nt < 4; nt++) acc[mi][nt] = (floatx4){0.f, 0.f, 0.f, 0.f};
        for (int ks = 0; ks < 8; ks++) {
            short8 Bf[4];
#pragma unroll
            for (int nt = 0; nt < 4; nt++) {
                int col = nt * 16 + n;
                Bf[nt] = *(const short8*)&X[col * XES + ks * 32 + q * 8];
            }
#pragma unroll
            for (int mi = 0; mi < 4; mi++) {
                short8 A = *(const short8*)(wpO + ((size_t)((mtb + mi) * 8 + ks) * 64 + lane) * 8);
#pragma unroll
                for (int nt = 0; nt < 4; nt++)
                    acc[mi][nt] = MFMA16(A, Bf[nt], acc[mi][nt], 0, 0, 0);
            }
        }
#pragma unroll
        for (int mi = 0; mi < 4; mi++) {
            int ch0 = 16 * (mtb + mi) + 4 * q;
#pragma unroll
            for (int nt = 0; nt < 4; nt++) {
                int col = nt * 16 + n;
                float v0 = fmaxf(acc[mi][nt][0] + BF[ch0], 0.f);
                float v1 = fmaxf(acc[mi][nt][1] + BF[ch0 + 1], 0.f);
                float v2 = fmaxf(acc[mi][nt][2] + BF[ch0 + 2], 0.f);
                float v3 = fmaxf(acc[mi][nt][3] + BF[ch0 + 3], 0.f);
                *(unsigned*)&E[col * XES + ch0]     = cvt_pk_bf16(v0, v1);
                *(unsigned*)&E[col * XES + ch0 + 2] = cvt_pk_bf16(v2, v3);
            }
        }
    }
    __syncthreads();
    {
        floatx4 acc[4][4];
#pragma unroll
        for (int mi = 0; mi < 4; mi++)
#pragma unroll
            for (int nt = 0; nt < 4; nt++) acc[mi][nt] = (floatx4){0.f, 0.f, 0.f, 0.f};
        for (int ks = 0; ks < 8; ks++) {
            short8 Bf[4];
#pragma unroll
            for (int nt = 0; nt < 4; nt++) {
                int col = nt * 16 + n;
                Bf[nt] = *(const short8*)&E[col * XES + ks * 32 + q * 8];
            }
#pragma unroll
            for (int mi = 0; mi < 4; mi++) {
                short8 A = *(const short8*)(wpE + ((size_t)((mtb + mi) * 8 + ks) * 64 + lane) * 8);
#pragma unroll
                for (int nt = 0; nt < 4; nt++)
                    acc[mi][nt] = MFMA16(A, Bf[nt], acc[mi][nt], 0, 0, 0);
            }
        }
#pragma unroll
        for (int mi = 0; mi < 4; mi++) {
            int r0 = 16 * (mtb + mi) + 4 * q;
#pragma unroll
            for (int nt = 0; nt < 4; nt++) {
                int t = t0 + nt * 16 + n;
#pragma unroll
                for (int r = 0; r < 4; r++)
                    io[((size_t)(b * NCLS) + r0 + r) * TLEN + t] =
                        acc[mi][nt][r] + BF[256 + r0 + r];
            }
        }
    }
}

extern "C" void kernel_launch(void* const* d_in, const int* in_sizes, int n_in,
                              void* d_out, int out_size, void* d_ws, size_t ws_size,
                              hipStream_t stream) {
    (void)in_sizes; (void)n_in;
    const float* wav    = (const float*)d_in[0];
    const float* cond   = (const float*)d_in[1];
    const float* wav_w  = (const float*)d_in[2];
    const float* wav_b  = (const float*)d_in[3];
    const float* cond_w = (const float*)d_in[4];
    const float* cond_b = (const float*)d_in[5];
    const float* dil_w  = (const float*)d_in[6];
    const float* dil_b  = (const float*)d_in[7];
    const float* skip_w = (const float*)d_in[8];
    const float* skip_b = (const float*)d_in[9];
    const float* res_w  = (const float*)d_in[10];
    const float* res_b  = (const float*)d_in[11];
    const float* out_w  = (const float*)d_in[12];
    const float* out_b  = (const float*)d_in[13];
    const float* end_w  = (const float*)d_in[14];
    const float* end_b  = (const float*)d_in[15];

    const size_t resElems = (size_t)BSZ * TLEN * CP;       // 16,777,216
    unsigned short* resA  = (unsigned short*)d_ws;
    unsigned short* resB  = resA + resElems;
    unsigned short* condp = resB + resElems;
    unsigned short* wp    = condp + (size_t)BSZ * TLEN * CC;
    float* bp             = (float*)(wp + (size_t)FR_TOT * 512);
    unsigned short* skipH = (unsigned short*)(bp + NBELEM);
    const size_t skipHBytes = (size_t)BSZ * SCH * TLEN * 2;  // 62,914,560
    const size_t needA = (size_t)((char*)(skipH) - (char*)d_ws) + skipHBytes;  // ~160 MB
    const bool hf = ws_size >= needA;

    void* skipPtr = hf ? (void*)skipH : (void*)d_out;
    // HF path: layer 0 WRITES skip (FIRST=true) -> no memset needed.
    if (!hf) hipMemsetAsync(d_out, 0, (size_t)out_size * sizeof(float), stream);

    k_packw<<<dim3((NWELEM + 255) / 256), 256, 0, stream>>>(
        dil_w, cond_w, skip_w, res_w, out_w, end_w, wp);
    k_packb<<<dim3((NBELEM + 255) / 256), 256, 0, stream>>>(
        dil_b, cond_b, skip_b, res_b, out_b, end_b, bp);
    k_init2<<<dim3(BSZ * TLEN / 4), 256, 0, stream>>>(wav, wav_w, wav_b, resA);
    k_packc<<<dim3(TLEN / 64, BSZ), 256, 0, stream>>>(cond, condp);

    unsigned short* rin = resA;
    unsigned short* rout = resB;
    for (int i = 0; i < NBLK; i++) {
        int d = 1 << (i & 7);
        if (hf) {
            if (i == 0)
                k_block4<true, true><<<dim3(TLEN / TSB, BSZ), 256, 0, stream>>>(
                    rin, rout, condp, skipPtr,
                    wp + (size_t)i * FR_BLK * 512, bp + (size_t)i * BIA_BLK, d);
            else
                k_block4<true, false><<<dim3(TLEN / TSB, BSZ), 256, 0, stream>>>(
                    rin, rout, condp, skipPtr,
                    wp + (size_t)i * FR_BLK * 512, bp + (size_t)i * BIA_BLK, d);
        } else {
            k_block4<false, false><<<dim3(TLEN / TSB, BSZ), 256, 0, stream>>>(
                rin, rout, condp, skipPtr,
                wp + (size_t)i * FR_BLK * 512, bp + (size_t)i * BIA_BLK, d);
        }
        unsigned short* tmp = rin; rin = rout; rout = tmp;
    }
    if (hf)
        k_final4<true><<<dim3(TLEN / TSF, BSZ), 256, 0, stream>>>(
            skipPtr, (float*)d_out,
            wp + (size_t)(NBLK * FR_BLK) * 512,
            wp + (size_t)(NBLK * FR_BLK + 128) * 512,
            bp + NBLK * BIA_BLK);
    else
        k_final4<false><<<dim3(TLEN / TSF, BSZ), 256, 0, stream>>>(
            skipPtr, (float*)d_out,
            wp + (size_t)(NBLK * FR_BLK) * 512,
            wp + (size_t)(NBLK * FR_BLK + 128) * 512,
            bp + NBLK * BIA_BLK);
}